// Round 9
// baseline (3393.659 us; speedup 1.0000x reference)
//
#include <hip/hip_runtime.h>
#include <hip/hip_cooperative_groups.h>
#include <math.h>

namespace cg = cooperative_groups;

#define T 32000
#define B 8
#define RES 32
#define SKIPC 32
#define NDIL 10
#define NLAYERS 20
#define GRID_RES 1000          // persistent blocks; 2000 tiles -> 2 per block

typedef __attribute__((ext_vector_type(8))) _Float16 half8;
typedef __attribute__((ext_vector_type(4))) _Float16 half4;
typedef __attribute__((ext_vector_type(4))) float float4v;

// ---------------- fast transcendentals ----------------
__device__ __forceinline__ float fast_rcp(float x) { return __builtin_amdgcn_rcpf(x); }
__device__ __forceinline__ float fast_exp2(float x) { return __builtin_amdgcn_exp2f(x); }
__device__ __forceinline__ float fast_sigmoid(float x) {
    return fast_rcp(1.f + fast_exp2(-1.4426950408889634f * x));
}
__device__ __forceinline__ float fast_tanh(float x) {
    return 1.f - 2.f * fast_rcp(1.f + fast_exp2(2.8853900817779268f * x));
}

// ---------------- weight repack to fp16 ----------------
__global__ void repack_weights_f16(const float* __restrict__ w1,
                                   const float* __restrict__ w2,
                                   _Float16* __restrict__ w1f,
                                   _Float16* __restrict__ w2f) {
    int idx = blockIdx.x * blockDim.x + threadIdx.x;
    if (idx < NDIL * 3 * 64 * 32) {
        int i = idx;
        int c = i % 32; i /= 32;
        int o = i % 64; i /= 64;
        int kt = i % 3; i /= 3;
        int l = i;
        w1f[idx] = (_Float16)w1[((l * 64 + o) * 32 + c) * 3 + kt];
    }
    if (idx < NDIL * 64 * 32) {
        w2f[idx] = (_Float16)w2[idx];
    }
}

// ---------------- conv1 ----------------
__global__ void conv1_kernel(const float* __restrict__ x,
                             const float* __restrict__ w,
                             float* __restrict__ h) {
    int t = blockIdx.x * blockDim.x + threadIdx.x;
    int b = blockIdx.y;
    if (t >= T) return;
    const float* xb = x + (size_t)b * T;
    float x2 = xb[t];
    float x1 = (t >= 1) ? xb[t - 1] : 0.f;
    float x0 = (t >= 2) ? xb[t - 2] : 0.f;
#pragma unroll
    for (int o = 0; o < RES; o++) {
        float v = w[o * 3 + 0] * x0 + w[o * 3 + 1] * x1 + w[o * 3 + 2] * x2;
        h[((size_t)(b * RES + o)) * T + t] = v;
    }
}

// ================= res-layer tile body (shared by both paths) =================
// Xs: [3][128][40] fp16; Gs aliases Xs[2] (safe: kt=2 consumed into regs
// before gate; a barrier separates last Xs read from first Gs write).
struct TileCtx {
    int lane, wv, n0, lcol, q;
};

template <bool ACC_SKIP_REG>
__device__ __forceinline__ void res_tile(
        const float* __restrict__ h_in, float* __restrict__ h_out,
        float* __restrict__ skip, float* skacc, bool first_layer,
        const _Float16* __restrict__ w1l, const _Float16* __restrict__ w2l,
        int d, int b, int t0, int tid, const TileCtx& cx,
        _Float16 (*Xs)[128][40]) {
    _Float16 (*Gs)[40] = Xs[2];   // overlay

    const float* hb = h_in + (size_t)b * RES * T;

    // ---- stage X taps ----
    {
        const int n = tid & 127;
        const int cg2 = tid >> 7;
        const int c0 = cg2 * 16;
        const int t = t0 + n;
        if (t0 >= 2 * d) {
#pragma unroll
            for (int kt = 0; kt < 3; kt++) {
                const int ts = t - (2 - kt) * d;
                const float* hp = hb + ts;
                half8 p0, p1;
#pragma unroll
                for (int i = 0; i < 8; i++) {
                    p0[i] = (_Float16)hp[(size_t)(c0 + i) * T];
                    p1[i] = (_Float16)hp[(size_t)(c0 + 8 + i) * T];
                }
                *(half8*)&Xs[kt][n][c0] = p0;
                *(half8*)&Xs[kt][n][c0 + 8] = p1;
            }
        } else {
#pragma unroll
            for (int kt = 0; kt < 3; kt++) {
                const int ts = t - (2 - kt) * d;
                const bool ok = ts >= 0;
                const float* hp = hb + (ok ? ts : 0);
                half8 p0, p1;
#pragma unroll
                for (int i = 0; i < 8; i++) {
                    float a = ok ? hp[(size_t)(c0 + i) * T] : 0.f;
                    float bb = ok ? hp[(size_t)(c0 + 8 + i) * T] : 0.f;
                    p0[i] = (_Float16)a;
                    p1[i] = (_Float16)bb;
                }
                *(half8*)&Xs[kt][n][c0] = p0;
                *(half8*)&Xs[kt][n][c0 + 8] = p1;
            }
        }
    }
    __syncthreads();

    const int n0 = cx.n0, lcol = cx.lcol, q = cx.q;

    // ---- GEMM1 ----
    float4v acc[4][2];
#pragma unroll
    for (int mt = 0; mt < 4; mt++)
#pragma unroll
        for (int nt = 0; nt < 2; nt++) acc[mt][nt] = (float4v)(0.f);

    half8 bf[2][3];
#pragma unroll
    for (int nt = 0; nt < 2; nt++)
#pragma unroll
        for (int kt = 0; kt < 3; kt++)
            bf[nt][kt] = *(const half8*)&Xs[kt][n0 + nt * 16 + lcol][q * 8];

#pragma unroll
    for (int mt = 0; mt < 4; mt++) {
#pragma unroll
        for (int kt = 0; kt < 3; kt++) {
            half8 af = *(const half8*)(w1l +
                ((size_t)(kt * 64 + mt * 16 + lcol) * 32 + q * 8));
#pragma unroll
            for (int nt = 0; nt < 2; nt++)
                acc[mt][nt] = __builtin_amdgcn_mfma_f32_16x16x32_f16(
                    af, bf[nt][kt], acc[mt][nt], 0, 0, 0);
        }
    }

    // ---- gate into registers ----
    half4 gh[2][2];
#pragma unroll
    for (int pp = 0; pp < 2; pp++)
#pragma unroll
        for (int nt = 0; nt < 2; nt++)
#pragma unroll
            for (int r = 0; r < 4; r++) {
                float a0 = acc[pp][nt][r];
                float a1 = acc[pp + 2][nt][r];
                gh[pp][nt][r] = (_Float16)(fast_tanh(a0) * fast_sigmoid(a1));
            }

    __syncthreads();   // all waves done reading Xs[2] before Gs overlay write

#pragma unroll
    for (int pp = 0; pp < 2; pp++)
#pragma unroll
        for (int nt = 0; nt < 2; nt++)
            *(half4*)&Gs[n0 + nt * 16 + lcol][pp * 16 + q * 4] = gh[pp][nt];
    __syncthreads();

    // ---- skip prefetch (RMW path only) ----
    const int tcol = t0 + n0;
    float skv[16];
    if (!ACC_SKIP_REG && !first_layer) {
#pragma unroll
        for (int mt = 0; mt < 2; mt++)
#pragma unroll
            for (int nt = 0; nt < 2; nt++)
#pragma unroll
                for (int r = 0; r < 4; r++) {
                    int o = mt * 16 + q * 4 + r;
                    int t = tcol + nt * 16 + lcol;
                    skv[(mt * 2 + nt) * 4 + r] =
                        skip[((size_t)(b * SKIPC + o)) * T + t];
                }
    }

    // ---- GEMM2 ----
    float4v zacc[4][2];
#pragma unroll
    for (int mt = 0; mt < 4; mt++)
#pragma unroll
        for (int nt = 0; nt < 2; nt++) zacc[mt][nt] = (float4v)(0.f);

    half8 gb[2];
#pragma unroll
    for (int nt = 0; nt < 2; nt++)
        gb[nt] = *(const half8*)&Gs[n0 + nt * 16 + lcol][q * 8];

#pragma unroll
    for (int mt = 0; mt < 4; mt++) {
        half8 af = *(const half8*)(w2l + ((size_t)(mt * 16 + lcol) * 32 + q * 8));
#pragma unroll
        for (int nt = 0; nt < 2; nt++)
            zacc[mt][nt] = __builtin_amdgcn_mfma_f32_16x16x32_f16(
                af, gb[nt], zacc[mt][nt], 0, 0, 0);
    }

    // ---- epilogue ----
#pragma unroll
    for (int mt = 0; mt < 2; mt++)
#pragma unroll
        for (int nt = 0; nt < 2; nt++)
#pragma unroll
            for (int r = 0; r < 4; r++) {
                int o = mt * 16 + q * 4 + r;
                int t = tcol + nt * 16 + lcol;
                size_t off = ((size_t)(b * RES + o)) * T + t;
                h_out[off] = h_in[off] + zacc[mt][nt][r];
            }
#pragma unroll
    for (int mt = 0; mt < 2; mt++)
#pragma unroll
        for (int nt = 0; nt < 2; nt++)
#pragma unroll
            for (int r = 0; r < 4; r++) {
                int idx = (mt * 2 + nt) * 4 + r;
                float z = zacc[mt + 2][nt][r];
                if (ACC_SKIP_REG) {
                    if (first_layer) skacc[idx] = z;
                    else             skacc[idx] += z;
                } else {
                    int o = mt * 16 + q * 4 + r;
                    int t = tcol + nt * 16 + lcol;
                    size_t off = ((size_t)(b * SKIPC + o)) * T + t;
                    if (first_layer) skip[off] = z;
                    else             skip[off] = skv[idx] + z;
                }
            }
}

// ---------------- cooperative: all 20 layers, skip in registers ----------------
__global__ __launch_bounds__(256, 4) void res_all(
        float* __restrict__ hA, float* __restrict__ hB,
        float* __restrict__ skip,
        const _Float16* __restrict__ w1f,
        const _Float16* __restrict__ w2f) {
    cg::grid_group grid = cg::this_grid();
    __shared__ _Float16 Xs[3][128][40];   // 30720 B (Gs overlays Xs[2])

    const int tid = threadIdx.x;
    const int g = blockIdx.x;
    TileCtx cx;
    cx.lane = tid & 63; cx.wv = tid >> 6; cx.n0 = cx.wv * 32;
    cx.lcol = cx.lane & 15; cx.q = cx.lane >> 4;

    float skacc[2][16];

    for (int l = 0; l < NLAYERS; l++) {
        const int il = l % NDIL;
        const int d = 1 << il;
        const float* h_in  = (l & 1) ? hB : hA;
        float*       h_out = (l & 1) ? hA : hB;
        const _Float16* w1l = w1f + (size_t)il * 3 * 64 * 32;
        const _Float16* w2l = w2f + (size_t)il * 64 * 32;

#pragma unroll 1
        for (int s = 0; s < 2; s++) {
            const int tile = g + s * GRID_RES;
            const int b = tile / 250;
            const int t0 = (tile % 250) * 128;
            __syncthreads();   // protect LDS from previous tile's readers
            res_tile<true>(h_in, h_out, skip, skacc[s], (l == 0),
                           w1l, w2l, d, b, t0, tid, cx, Xs);
        }
        grid.sync();
    }

#pragma unroll 1
    for (int s = 0; s < 2; s++) {
        const int tile = g + s * GRID_RES;
        const int b = tile / 250;
        const int t0 = (tile % 250) * 128;
        const int tcol = t0 + cx.n0;
#pragma unroll
        for (int mt = 0; mt < 2; mt++)
#pragma unroll
            for (int nt = 0; nt < 2; nt++)
#pragma unroll
                for (int r = 0; r < 4; r++) {
                    int o = mt * 16 + cx.q * 4 + r;
                    int t = tcol + nt * 16 + cx.lcol;
                    skip[((size_t)(b * SKIPC + o)) * T + t] =
                        skacc[s][(mt * 2 + nt) * 4 + r];
                }
    }
}

// ---------------- fallback: one layer per launch (R7, proven) ----------------
template <bool FIRST>
__global__ __launch_bounds__(256) void res_layer_mfma(
        const float* __restrict__ h_in, float* __restrict__ h_out,
        float* __restrict__ skip,
        const _Float16* __restrict__ w1l,
        const _Float16* __restrict__ w2l,
        int d) {
    __shared__ _Float16 Xs[3][128][40];
    const int tid = threadIdx.x;
    TileCtx cx;
    cx.lane = tid & 63; cx.wv = tid >> 6; cx.n0 = cx.wv * 32;
    cx.lcol = cx.lane & 15; cx.q = cx.lane >> 4;
    res_tile<false>(h_in, h_out, skip, nullptr, FIRST,
                    w1l, w2l, d, blockIdx.y, blockIdx.x * 128, tid, cx, Xs);
}

// ---------------- post chain ----------------
__global__ void post2_kernel(const float* __restrict__ skip,
                             const float* __restrict__ w,
                             float* __restrict__ out16) {
    int t = blockIdx.x * blockDim.x + threadIdx.x;
    int b = blockIdx.y;
    float acc[16];
#pragma unroll
    for (int o = 0; o < 16; o++) acc[o] = 0.f;
    for (int c = 0; c < 32; c++) {
        const float* sc = skip + ((size_t)(b * 32 + c)) * T;
        float v2 = fast_tanh(sc[t]);
        float v1 = (t >= 1) ? fast_tanh(sc[t - 1]) : 0.f;
        float v0 = (t >= 2) ? fast_tanh(sc[t - 2]) : 0.f;
#pragma unroll
        for (int o = 0; o < 16; o++) {
            const float* wo = w + (o * 32 + c) * 3;
            acc[o] += wo[0] * v0 + wo[1] * v1 + wo[2] * v2;
        }
    }
#pragma unroll
    for (int o = 0; o < 16; o++)
        out16[((size_t)(b * 16 + o)) * T + t] = fast_tanh(acc[o]);
}

__global__ void post3_kernel(const float* __restrict__ in16,
                             const float* __restrict__ w,
                             float* __restrict__ out8) {
    int t = blockIdx.x * blockDim.x + threadIdx.x;
    int b = blockIdx.y;
    float acc[8];
#pragma unroll
    for (int o = 0; o < 8; o++) acc[o] = 0.f;
    for (int c = 0; c < 16; c++) {
        const float* sc = in16 + ((size_t)(b * 16 + c)) * T;
        float v2 = sc[t];
        float v1 = (t >= 1) ? sc[t - 1] : 0.f;
        float v0 = (t >= 2) ? sc[t - 2] : 0.f;
#pragma unroll
        for (int o = 0; o < 8; o++) {
            const float* wo = w + (o * 16 + c) * 3;
            acc[o] += wo[0] * v0 + wo[1] * v1 + wo[2] * v2;
        }
    }
#pragma unroll
    for (int o = 0; o < 8; o++)
        out8[((size_t)(b * 8 + o)) * T + t] = fast_tanh(acc[o]);
}

__global__ void post4_kernel(const float* __restrict__ in8,
                             const float* __restrict__ w,
                             float* __restrict__ out1) {
    int t = blockIdx.x * blockDim.x + threadIdx.x;
    int b = blockIdx.y;
    float acc = 0.f;
#pragma unroll
    for (int c = 0; c < 8; c++) {
        const float* sc = in8 + ((size_t)(b * 8 + c)) * T;
        float v2 = sc[t];
        float v1 = (t >= 1) ? sc[t - 1] : 0.f;
        float v0 = (t >= 2) ? sc[t - 2] : 0.f;
        const float* wo = w + c * 3;
        acc += wo[0] * v0 + wo[1] * v1 + wo[2] * v2;
    }
    out1[(size_t)b * T + t] = fast_tanh(acc);
}

__global__ void vnn_kernel(const float* __restrict__ in1,
                           const float* __restrict__ w1,
                           const float* __restrict__ w2,
                           float* __restrict__ out) {
    int t = blockIdx.x * blockDim.x + threadIdx.x;
    int b = blockIdx.y;
    const float* xb = in1 + (size_t)b * T;
    float tap[16];
#pragma unroll
    for (int k = 0; k < 16; k++) {
        int ti = t - 15 + k;
        tap[k] = (ti >= 0) ? xb[ti] : 0.f;
    }
    float lin = 0.f;
#pragma unroll
    for (int k = 0; k < 16; k++) lin += w1[k] * tap[k];
    float s[6];
#pragma unroll
    for (int q = 0; q < 6; q++) {
        float a = 0.f;
#pragma unroll
        for (int k = 0; k < 16; k++) a += w2[q * 16 + k] * tap[k];
        s[q] = a;
    }
    float quad = s[0] * s[3] + s[1] * s[4] + s[2] * s[5];
    out[(size_t)b * T + t] = lin + quad;
}

extern "C" void kernel_launch(void* const* d_in, const int* in_sizes, int n_in,
                              void* d_out, int out_size, void* d_ws, size_t ws_size,
                              hipStream_t stream) {
    const float* x       = (const float*)d_in[0];
    const float* conv1_w = (const float*)d_in[1];
    const float* res_w1  = (const float*)d_in[2];
    const float* res_w2  = (const float*)d_in[3];
    const float* post2_w = (const float*)d_in[4];
    const float* post3_w = (const float*)d_in[5];
    const float* post4_w = (const float*)d_in[6];
    const float* vnn1_w  = (const float*)d_in[7];
    const float* vnn2_w  = (const float*)d_in[8];
    float* out = (float*)d_out;

    char* ws = (char*)d_ws;
    const size_t SZ_H    = (size_t)B * RES * T * 4;
    const size_t SZ_O16  = (size_t)B * 16 * T * 4;
    const size_t SZ_O8   = (size_t)B * 8 * T * 4;
    const size_t SZ_O1   = (size_t)B * 1 * T * 4;
    float*     hA    = (float*)(ws);
    float*     hB    = (float*)(ws + SZ_H);
    float*     skip  = (float*)(ws + 2 * SZ_H);
    float*     out16 = (float*)(ws + 3 * SZ_H);
    float*     out8  = (float*)(ws + 3 * SZ_H + SZ_O16);
    float*     out1  = (float*)(ws + 3 * SZ_H + SZ_O16 + SZ_O8);
    _Float16*  w1f   = (_Float16*)(ws + 3 * SZ_H + SZ_O16 + SZ_O8 + SZ_O1);
    _Float16*  w2f   = (_Float16*)(ws + 3 * SZ_H + SZ_O16 + SZ_O8 + SZ_O1
                                      + (size_t)NDIL * 3 * 64 * 32 * 2);

    dim3 blk(256);
    dim3 grd(T / 256, B);
    dim3 grdR(T / 128, B);

    repack_weights_f16<<<dim3((NDIL * 3 * 64 * 32 + 255) / 256), blk, 0, stream>>>(
        res_w1, res_w2, w1f, w2f);

    conv1_kernel<<<grd, blk, 0, stream>>>(x, conv1_w, hA);

    // cooperative path: all 20 layers, skip held in registers
    void* kargs[] = { (void*)&hA, (void*)&hB, (void*)&skip,
                      (void*)&w1f, (void*)&w2f };
    hipError_t cerr = hipLaunchCooperativeKernel(
        (void*)res_all, dim3(GRID_RES), dim3(256), kargs, 0, stream);
    if (cerr != hipSuccess) {
        (void)hipGetLastError();   // clear sticky error
        // fallback: per-layer launches (proven R7 path)
        const float* cur = hA;
        float* nxt = hB;
        for (int l = 0; l < NLAYERS; l++) {
            int i = l % NDIL;
            int d = 1 << i;
            const _Float16* w1l = w1f + (size_t)i * 3 * 64 * 32;
            const _Float16* w2l = w2f + (size_t)i * 64 * 32;
            if (l == 0)
                res_layer_mfma<true><<<grdR, blk, 0, stream>>>(cur, nxt, skip, w1l, w2l, d);
            else
                res_layer_mfma<false><<<grdR, blk, 0, stream>>>(cur, nxt, skip, w1l, w2l, d);
            const float* tmp = nxt;
            nxt = (float*)cur;
            cur = tmp;
        }
    }

    post2_kernel<<<grd, blk, 0, stream>>>(skip, post2_w, out16);
    post3_kernel<<<grd, blk, 0, stream>>>(out16, post3_w, out8);
    post4_kernel<<<grd, blk, 0, stream>>>(out8, post4_w, out1);
    vnn_kernel<<<grd, blk, 0, stream>>>(out1, vnn1_w, vnn2_w, out);
}

// Round 10
// 898.219 us; speedup vs baseline: 3.7782x; 3.7782x over previous
//
#include <hip/hip_runtime.h>
#include <math.h>

#define T 32000
#define B 8
#define RES 32
#define SKIPC 32
#define NDIL 10
#define NLAYERS 20

typedef __attribute__((ext_vector_type(8))) _Float16 half8;
typedef __attribute__((ext_vector_type(4))) _Float16 half4;
typedef __attribute__((ext_vector_type(4))) float float4v;

// ---------------- fast transcendentals ----------------
__device__ __forceinline__ float fast_rcp(float x) { return __builtin_amdgcn_rcpf(x); }
__device__ __forceinline__ float fast_exp2(float x) { return __builtin_amdgcn_exp2f(x); }
__device__ __forceinline__ float fast_sigmoid(float x) {
    return fast_rcp(1.f + fast_exp2(-1.4426950408889634f * x));
}
__device__ __forceinline__ float fast_tanh(float x) {
    return 1.f - 2.f * fast_rcp(1.f + fast_exp2(2.8853900817779268f * x));
}

// ---------------- weight repack to fp16 ----------------
// res_w1: [10][64][32][3] -> w1f: [10][3][64][32] fp16  (tap-major, c contig)
// res_w2: [10][64][32]    -> w2f: [10][64][32] fp16
__global__ void repack_weights_f16(const float* __restrict__ w1,
                                   const float* __restrict__ w2,
                                   _Float16* __restrict__ w1f,
                                   _Float16* __restrict__ w2f) {
    int idx = blockIdx.x * blockDim.x + threadIdx.x;
    if (idx < NDIL * 3 * 64 * 32) {
        int i = idx;
        int c = i % 32; i /= 32;
        int o = i % 64; i /= 64;
        int kt = i % 3; i /= 3;
        int l = i;
        w1f[idx] = (_Float16)w1[((l * 64 + o) * 32 + c) * 3 + kt];
    }
    if (idx < NDIL * 64 * 32) {
        w2f[idx] = (_Float16)w2[idx];
    }
}

// ---------------- conv1: [B,1,T] -> h[B][T][RES] (channel-contiguous) -------
__global__ void conv1_kernel(const float* __restrict__ x,
                             const float* __restrict__ w,   // [32][1][3]
                             float* __restrict__ h) {
    int t = blockIdx.x * blockDim.x + threadIdx.x;
    int b = blockIdx.y;
    if (t >= T) return;
    const float* xb = x + (size_t)b * T;
    float x2 = xb[t];
    float x1 = (t >= 1) ? xb[t - 1] : 0.f;
    float x0 = (t >= 2) ? xb[t - 2] : 0.f;
    float* hr = h + ((size_t)b * T + t) * RES;
#pragma unroll
    for (int o = 0; o < RES; o += 4) {
        float4v v;
#pragma unroll
        for (int r = 0; r < 4; r++)
            v[r] = w[(o + r) * 3 + 0] * x0 + w[(o + r) * 3 + 1] * x1
                 + w[(o + r) * 3 + 2] * x2;
        *(float4v*)(hr + o) = v;
    }
}

// ---------------- residual layer via f16 MFMA, [B][T][C] layout -------------
// Block = 256 threads = 4 waves; t-tile of 128. h/skip channel-contiguous:
// staging = 12 float4 loads/thread, epilogue = float4 RMW (4x fewer VMEM
// instructions than R7's scalar version — R7 was latency/issue-bound at
// VALUBusy 12%, HBM 46%).
template <bool FIRST>
__global__ __launch_bounds__(256) void res_layer_mfma(
        const float* __restrict__ h_in, float* __restrict__ h_out,
        float* __restrict__ skip,
        const _Float16* __restrict__ w1l,   // [3][64][32] this layer
        const _Float16* __restrict__ w2l,   // [64][32] this layer
        int d) {
    __shared__ _Float16 Xs[3][128][40];     // 30720 B; Gs overlays Xs[2]
    _Float16 (*Gs)[40] = Xs[2];

    const int tid = threadIdx.x;
    const int t0 = blockIdx.x * 128;
    const int b = blockIdx.y;
    const float* hb = h_in + (size_t)b * T * RES;

    // ---- stage X taps: thread (n = tid&127, cg = tid>>7) loads 16 channels ----
    {
        const int n = tid & 127;
        const int c0 = (tid >> 7) * 16;
        const int t = t0 + n;
#pragma unroll
        for (int kt = 0; kt < 3; kt++) {
            const int ts = t - (2 - kt) * d;
            const bool ok = ts >= 0;
            const float* row = hb + (size_t)(ok ? ts : 0) * RES + c0;
            float4v f0 = *(const float4v*)(row);
            float4v f1 = *(const float4v*)(row + 4);
            float4v f2 = *(const float4v*)(row + 8);
            float4v f3 = *(const float4v*)(row + 12);
            half8 p0, p1;
#pragma unroll
            for (int i = 0; i < 4; i++) {
                p0[i]     = ok ? (_Float16)f0[i] : (_Float16)0.f;
                p0[4 + i] = ok ? (_Float16)f1[i] : (_Float16)0.f;
                p1[i]     = ok ? (_Float16)f2[i] : (_Float16)0.f;
                p1[4 + i] = ok ? (_Float16)f3[i] : (_Float16)0.f;
            }
            *(half8*)&Xs[kt][n][c0] = p0;
            *(half8*)&Xs[kt][n][c0 + 8] = p1;
        }
    }
    __syncthreads();

    const int lane = tid & 63;
    const int wv = tid >> 6;
    const int n0 = wv * 32;
    const int lcol = lane & 15;
    const int q = lane >> 4;

    // ---- GEMM1: conv ----
    float4v acc[4][2];
#pragma unroll
    for (int mt = 0; mt < 4; mt++)
#pragma unroll
        for (int nt = 0; nt < 2; nt++) acc[mt][nt] = (float4v)(0.f);

    half8 bf[2][3];
#pragma unroll
    for (int nt = 0; nt < 2; nt++)
#pragma unroll
        for (int kt = 0; kt < 3; kt++)
            bf[nt][kt] = *(const half8*)&Xs[kt][n0 + nt * 16 + lcol][q * 8];

#pragma unroll
    for (int mt = 0; mt < 4; mt++) {
#pragma unroll
        for (int kt = 0; kt < 3; kt++) {
            half8 af = *(const half8*)(w1l +
                ((size_t)(kt * 64 + mt * 16 + lcol) * 32 + q * 8));
#pragma unroll
            for (int nt = 0; nt < 2; nt++)
                acc[mt][nt] = __builtin_amdgcn_mfma_f32_16x16x32_f16(
                    af, bf[nt][kt], acc[mt][nt], 0, 0, 0);
        }
    }

    // ---- gate into registers; then overlay Gs onto Xs[2] ----
    half4 gh[2][2];
#pragma unroll
    for (int pp = 0; pp < 2; pp++)
#pragma unroll
        for (int nt = 0; nt < 2; nt++)
#pragma unroll
            for (int r = 0; r < 4; r++) {
                float a0 = acc[pp][nt][r];
                float a1 = acc[pp + 2][nt][r];
                gh[pp][nt][r] = (_Float16)(fast_tanh(a0) * fast_sigmoid(a1));
            }

    __syncthreads();   // all waves done reading Xs[2] before overlay write

#pragma unroll
    for (int pp = 0; pp < 2; pp++)
#pragma unroll
        for (int nt = 0; nt < 2; nt++)
            *(half4*)&Gs[n0 + nt * 16 + lcol][pp * 16 + q * 4] = gh[pp][nt];
    __syncthreads();

    // ---- skip prefetch (float4; latency hides under GEMM2) ----
    // this lane owns (o = mt*16 + q*4 .. +3, t = tcol + nt*16 + lcol)
    const int tcol = t0 + n0;
    float4v skv[2][2];
    if (!FIRST) {
#pragma unroll
        for (int mt = 0; mt < 2; mt++)
#pragma unroll
            for (int nt = 0; nt < 2; nt++) {
                int t = tcol + nt * 16 + lcol;
                skv[mt][nt] = *(const float4v*)(skip +
                    ((size_t)b * T + t) * SKIPC + mt * 16 + q * 4);
            }
    }

    // ---- GEMM2: 1x1 ----
    float4v zacc[4][2];
#pragma unroll
    for (int mt = 0; mt < 4; mt++)
#pragma unroll
        for (int nt = 0; nt < 2; nt++) zacc[mt][nt] = (float4v)(0.f);

    half8 gb[2];
#pragma unroll
    for (int nt = 0; nt < 2; nt++)
        gb[nt] = *(const half8*)&Gs[n0 + nt * 16 + lcol][q * 8];

#pragma unroll
    for (int mt = 0; mt < 4; mt++) {
        half8 af = *(const half8*)(w2l + ((size_t)(mt * 16 + lcol) * 32 + q * 8));
#pragma unroll
        for (int nt = 0; nt < 2; nt++)
            zacc[mt][nt] = __builtin_amdgcn_mfma_f32_16x16x32_f16(
                af, gb[nt], zacc[mt][nt], 0, 0, 0);
    }

    // ---- epilogue: float4 everywhere ----
#pragma unroll
    for (int mt = 0; mt < 2; mt++)
#pragma unroll
        for (int nt = 0; nt < 2; nt++) {
            int t = tcol + nt * 16 + lcol;
            size_t off = ((size_t)b * T + t) * RES + mt * 16 + q * 4;
            float4v hv = *(const float4v*)(h_in + off);
            *(float4v*)(h_out + off) = hv + zacc[mt][nt];
        }
#pragma unroll
    for (int mt = 0; mt < 2; mt++)
#pragma unroll
        for (int nt = 0; nt < 2; nt++) {
            int t = tcol + nt * 16 + lcol;
            size_t off = ((size_t)b * T + t) * SKIPC + mt * 16 + q * 4;
            float4v z = zacc[mt + 2][nt];
            if (FIRST) *(float4v*)(skip + off) = z;
            else       *(float4v*)(skip + off) = skv[mt][nt] + z;
        }
}

// ---------------- post2: tanh(skip[B][T][32]) -> conv 32->16 k3 -> tanh -----
// out16 stays [B][16][T] for post3.
__global__ void post2_kernel(const float* __restrict__ skip,
                             const float* __restrict__ w,    // [16][32][3]
                             float* __restrict__ out16) {
    int t = blockIdx.x * blockDim.x + threadIdx.x;
    int b = blockIdx.y;
    float sv[3][32];
#pragma unroll
    for (int k = 0; k < 3; k++) {
        int ts = t - (2 - k);
        bool ok = ts >= 0;
        const float* row = skip + ((size_t)b * T + (ok ? ts : 0)) * SKIPC;
#pragma unroll
        for (int c = 0; c < 32; c += 4) {
            float4v v = *(const float4v*)(row + c);
#pragma unroll
            for (int r = 0; r < 4; r++)
                sv[k][c + r] = ok ? fast_tanh(v[r]) : 0.f;
        }
    }
    float acc[16];
#pragma unroll
    for (int o = 0; o < 16; o++) acc[o] = 0.f;
#pragma unroll
    for (int c = 0; c < 32; c++) {
#pragma unroll
        for (int o = 0; o < 16; o++) {
            const float* wo = w + (o * 32 + c) * 3;
            acc[o] += wo[0] * sv[0][c] + wo[1] * sv[1][c] + wo[2] * sv[2][c];
        }
    }
#pragma unroll
    for (int o = 0; o < 16; o++)
        out16[((size_t)(b * 16 + o)) * T + t] = fast_tanh(acc[o]);
}

// ---------------- post3: conv 16->8 k3 -> tanh ----------------
__global__ void post3_kernel(const float* __restrict__ in16,
                             const float* __restrict__ w,    // [8][16][3]
                             float* __restrict__ out8) {
    int t = blockIdx.x * blockDim.x + threadIdx.x;
    int b = blockIdx.y;
    float acc[8];
#pragma unroll
    for (int o = 0; o < 8; o++) acc[o] = 0.f;
    for (int c = 0; c < 16; c++) {
        const float* sc = in16 + ((size_t)(b * 16 + c)) * T;
        float v2 = sc[t];
        float v1 = (t >= 1) ? sc[t - 1] : 0.f;
        float v0 = (t >= 2) ? sc[t - 2] : 0.f;
#pragma unroll
        for (int o = 0; o < 8; o++) {
            const float* wo = w + (o * 16 + c) * 3;
            acc[o] += wo[0] * v0 + wo[1] * v1 + wo[2] * v2;
        }
    }
#pragma unroll
    for (int o = 0; o < 8; o++)
        out8[((size_t)(b * 8 + o)) * T + t] = fast_tanh(acc[o]);
}

// ---------------- post4: conv 8->1 k3 -> tanh ----------------
__global__ void post4_kernel(const float* __restrict__ in8,
                             const float* __restrict__ w,    // [1][8][3]
                             float* __restrict__ out1) {
    int t = blockIdx.x * blockDim.x + threadIdx.x;
    int b = blockIdx.y;
    float acc = 0.f;
#pragma unroll
    for (int c = 0; c < 8; c++) {
        const float* sc = in8 + ((size_t)(b * 8 + c)) * T;
        float v2 = sc[t];
        float v1 = (t >= 1) ? sc[t - 1] : 0.f;
        float v0 = (t >= 2) ? sc[t - 2] : 0.f;
        const float* wo = w + c * 3;
        acc += wo[0] * v0 + wo[1] * v1 + wo[2] * v2;
    }
    out1[(size_t)b * T + t] = fast_tanh(acc);
}

// ---------------- vnn head: lin(k=16) + quadratic Volterra ----------------
__global__ void vnn_kernel(const float* __restrict__ in1,   // [B][T]
                           const float* __restrict__ w1,    // [1][1][16]
                           const float* __restrict__ w2,    // [6][1][16]
                           float* __restrict__ out) {       // [B][T]
    int t = blockIdx.x * blockDim.x + threadIdx.x;
    int b = blockIdx.y;
    const float* xb = in1 + (size_t)b * T;
    float tap[16];
#pragma unroll
    for (int k = 0; k < 16; k++) {
        int ti = t - 15 + k;
        tap[k] = (ti >= 0) ? xb[ti] : 0.f;
    }
    float lin = 0.f;
#pragma unroll
    for (int k = 0; k < 16; k++) lin += w1[k] * tap[k];
    float s[6];
#pragma unroll
    for (int q = 0; q < 6; q++) {
        float a = 0.f;
#pragma unroll
        for (int k = 0; k < 16; k++) a += w2[q * 16 + k] * tap[k];
        s[q] = a;
    }
    float quad = s[0] * s[3] + s[1] * s[4] + s[2] * s[5];
    out[(size_t)b * T + t] = lin + quad;
}

extern "C" void kernel_launch(void* const* d_in, const int* in_sizes, int n_in,
                              void* d_out, int out_size, void* d_ws, size_t ws_size,
                              hipStream_t stream) {
    const float* x       = (const float*)d_in[0];
    const float* conv1_w = (const float*)d_in[1];
    const float* res_w1  = (const float*)d_in[2];
    const float* res_w2  = (const float*)d_in[3];
    const float* post2_w = (const float*)d_in[4];
    const float* post3_w = (const float*)d_in[5];
    const float* post4_w = (const float*)d_in[6];
    const float* vnn1_w  = (const float*)d_in[7];
    const float* vnn2_w  = (const float*)d_in[8];
    float* out = (float*)d_out;

    char* ws = (char*)d_ws;
    const size_t SZ_H    = (size_t)B * RES * T * 4;
    const size_t SZ_O16  = (size_t)B * 16 * T * 4;
    const size_t SZ_O8   = (size_t)B * 8 * T * 4;
    const size_t SZ_O1   = (size_t)B * 1 * T * 4;
    float*     hA    = (float*)(ws);
    float*     hB    = (float*)(ws + SZ_H);
    float*     skip  = (float*)(ws + 2 * SZ_H);
    float*     out16 = (float*)(ws + 3 * SZ_H);
    float*     out8  = (float*)(ws + 3 * SZ_H + SZ_O16);
    float*     out1  = (float*)(ws + 3 * SZ_H + SZ_O16 + SZ_O8);
    _Float16*  w1f   = (_Float16*)(ws + 3 * SZ_H + SZ_O16 + SZ_O8 + SZ_O1);
    _Float16*  w2f   = (_Float16*)(ws + 3 * SZ_H + SZ_O16 + SZ_O8 + SZ_O1
                                      + (size_t)NDIL * 3 * 64 * 32 * 2);

    dim3 blk(256);
    dim3 grd(T / 256, B);     // pre/post kernels: 125 x 8
    dim3 grdR(T / 128, B);    // res layers: 250 x 8

    repack_weights_f16<<<dim3((NDIL * 3 * 64 * 32 + 255) / 256), blk, 0, stream>>>(
        res_w1, res_w2, w1f, w2f);

    conv1_kernel<<<grd, blk, 0, stream>>>(x, conv1_w, hA);

    const float* cur = hA;
    float* nxt = hB;
    for (int l = 0; l < NLAYERS; l++) {
        int i = l % NDIL;
        int d = 1 << i;
        const _Float16* w1l = w1f + (size_t)i * 3 * 64 * 32;
        const _Float16* w2l = w2f + (size_t)i * 64 * 32;
        if (l == 0)
            res_layer_mfma<true><<<grdR, blk, 0, stream>>>(cur, nxt, skip, w1l, w2l, d);
        else
            res_layer_mfma<false><<<grdR, blk, 0, stream>>>(cur, nxt, skip, w1l, w2l, d);
        const float* tmp = nxt;
        nxt = (float*)cur;
        cur = tmp;
    }

    post2_kernel<<<grd, blk, 0, stream>>>(skip, post2_w, out16);
    post3_kernel<<<grd, blk, 0, stream>>>(out16, post3_w, out8);
    post4_kernel<<<grd, blk, 0, stream>>>(out8, post4_w, out1);
    vnn_kernel<<<grd, blk, 0, stream>>>(out1, vnn1_w, vnn2_w, out);
}

// Round 12
// 834.286 us; speedup vs baseline: 4.0677x; 1.0766x over previous
//
#include <hip/hip_runtime.h>
#include <math.h>

#define T 32000
#define B 8
#define RES 32
#define SKIPC 32
#define NDIL 10
#define NLAYERS 20

typedef __attribute__((ext_vector_type(8))) _Float16 half8;
typedef __attribute__((ext_vector_type(4))) _Float16 half4;
typedef __attribute__((ext_vector_type(4))) float float4v;

// ---------------- fast transcendentals ----------------
__device__ __forceinline__ float fast_rcp(float x) { return __builtin_amdgcn_rcpf(x); }
__device__ __forceinline__ float fast_exp2(float x) { return __builtin_amdgcn_exp2f(x); }
__device__ __forceinline__ float fast_sigmoid(float x) {
    return fast_rcp(1.f + fast_exp2(-1.4426950408889634f * x));
}
__device__ __forceinline__ float fast_tanh(float x) {
    return 1.f - 2.f * fast_rcp(1.f + fast_exp2(2.8853900817779268f * x));
}

// ---------------- weight repack to fp16 ----------------
// res_w1: [10][64][32][3] -> w1f: [10][3][64][32] fp16  (tap-major, c contig)
// res_w2: [10][64][32]    -> w2f: [10][64][32] fp16
__global__ void repack_weights_f16(const float* __restrict__ w1,
                                   const float* __restrict__ w2,
                                   _Float16* __restrict__ w1f,
                                   _Float16* __restrict__ w2f) {
    int idx = blockIdx.x * blockDim.x + threadIdx.x;
    if (idx < NDIL * 3 * 64 * 32) {
        int i = idx;
        int c = i % 32; i /= 32;
        int o = i % 64; i /= 64;
        int kt = i % 3; i /= 3;
        int l = i;
        w1f[idx] = (_Float16)w1[((l * 64 + o) * 32 + c) * 3 + kt];
    }
    if (idx < NDIL * 64 * 32) {
        w2f[idx] = (_Float16)w2[idx];
    }
}

// ---------------- conv1: [B,1,T] -> h[B][T][RES] (channel-contiguous) -------
__global__ void conv1_kernel(const float* __restrict__ x,
                             const float* __restrict__ w,   // [32][1][3]
                             float* __restrict__ h) {
    int t = blockIdx.x * blockDim.x + threadIdx.x;
    int b = blockIdx.y;
    if (t >= T) return;
    const float* xb = x + (size_t)b * T;
    float x2 = xb[t];
    float x1 = (t >= 1) ? xb[t - 1] : 0.f;
    float x0 = (t >= 2) ? xb[t - 2] : 0.f;
    float* hr = h + ((size_t)b * T + t) * RES;
#pragma unroll
    for (int o = 0; o < RES; o += 4) {
        float4v v;
#pragma unroll
        for (int r = 0; r < 4; r++)
            v[r] = w[(o + r) * 3 + 0] * x0 + w[(o + r) * 3 + 1] * x1
                 + w[(o + r) * 3 + 2] * x2;
        *(float4v*)(hr + o) = v;
    }
}

// ---------------- residual layer via f16 MFMA, barrier-free -----------------
// [B][T][C] layout: the MFMA B-fragment (8 consecutive channels at one t) is
// DIRECTLY addressable in global: h[(b*T + t)*32 + q*8]. No LDS X staging, no
// s_barrier. G exchange is intra-wave cross-lane via a wave-private LDS slab;
// __builtin_amdgcn_wave_barrier() pins compile-time ordering (DS ops are
// in-order per wave in HW).
// R11 bug fixed here: tap time index must include the wave column base n0
// (R11 omitted it -> all waves read wave-0's columns).
template <bool FIRST>
__global__ __launch_bounds__(256) void res_layer_mfma(
        const float* __restrict__ h_in, float* __restrict__ h_out,
        float* __restrict__ skip,
        const _Float16* __restrict__ w1l,   // [3][64][32] this layer
        const _Float16* __restrict__ w2l,   // [64][32] this layer
        int d) {
    __shared__ _Float16 Gs[4][32][40];      // 10240 B, per-wave slabs

    const int tid = threadIdx.x;
    const int t0 = blockIdx.x * 128;
    const int b = blockIdx.y;
    const int lane = tid & 63;
    const int wv = tid >> 6;
    const int n0 = wv * 32;
    const int lcol = lane & 15;
    const int q = lane >> 4;
    const float* hb = h_in + (size_t)b * T * RES;

    // ---- direct B-frag loads: 6 taps x (2 float4 + cvt) ----
    half8 bf[2][3];
    if (t0 >= 2 * d) {                      // interior block (uniform branch)
#pragma unroll
        for (int nt = 0; nt < 2; nt++)
#pragma unroll
            for (int kt = 0; kt < 3; kt++) {
                int tb = t0 + n0 + nt * 16 + lcol - (2 - kt) * d;
                const float* row = hb + (size_t)tb * RES + q * 8;
                float4v f0 = *(const float4v*)(row);
                float4v f1 = *(const float4v*)(row + 4);
                half8 p;
#pragma unroll
                for (int i = 0; i < 4; i++) {
                    p[i]     = (_Float16)f0[i];
                    p[4 + i] = (_Float16)f1[i];
                }
                bf[nt][kt] = p;
            }
    } else {
#pragma unroll
        for (int nt = 0; nt < 2; nt++)
#pragma unroll
            for (int kt = 0; kt < 3; kt++) {
                int tb = t0 + n0 + nt * 16 + lcol - (2 - kt) * d;
                bool ok = tb >= 0;
                const float* row = hb + (size_t)(ok ? tb : 0) * RES + q * 8;
                float4v f0 = *(const float4v*)(row);
                float4v f1 = *(const float4v*)(row + 4);
                half8 p;
#pragma unroll
                for (int i = 0; i < 4; i++) {
                    p[i]     = ok ? (_Float16)f0[i] : (_Float16)0.f;
                    p[4 + i] = ok ? (_Float16)f1[i] : (_Float16)0.f;
                }
                bf[nt][kt] = p;
            }
    }

    // ---- GEMM1: conv ----
    float4v acc[4][2];
#pragma unroll
    for (int mt = 0; mt < 4; mt++)
#pragma unroll
        for (int nt = 0; nt < 2; nt++) acc[mt][nt] = (float4v)(0.f);

#pragma unroll
    for (int mt = 0; mt < 4; mt++) {
#pragma unroll
        for (int kt = 0; kt < 3; kt++) {
            half8 af = *(const half8*)(w1l +
                ((size_t)(kt * 64 + mt * 16 + lcol) * 32 + q * 8));
#pragma unroll
            for (int nt = 0; nt < 2; nt++)
                acc[mt][nt] = __builtin_amdgcn_mfma_f32_16x16x32_f16(
                    af, bf[nt][kt], acc[mt][nt], 0, 0, 0);
        }
    }

    // ---- gate (lane-local o <-> o+32 pairing), write to wave-private LDS ----
#pragma unroll
    for (int pp = 0; pp < 2; pp++)
#pragma unroll
        for (int nt = 0; nt < 2; nt++) {
            half4 gh;
#pragma unroll
            for (int r = 0; r < 4; r++) {
                float a0 = acc[pp][nt][r];
                float a1 = acc[pp + 2][nt][r];
                gh[r] = (_Float16)(fast_tanh(a0) * fast_sigmoid(a1));
            }
            *(half4*)&Gs[wv][nt * 16 + lcol][pp * 16 + q * 4] = gh;
        }
    // cross-lane within wave: pin compiler ordering (HW DS ops in-order/wave)
    __builtin_amdgcn_wave_barrier();

    // ---- skip prefetch (float4; latency hides under GEMM2) ----
    const int tcol = t0 + n0;
    float4v skv[2][2];
    if (!FIRST) {
#pragma unroll
        for (int mt = 0; mt < 2; mt++)
#pragma unroll
            for (int nt = 0; nt < 2; nt++) {
                int t = tcol + nt * 16 + lcol;
                skv[mt][nt] = *(const float4v*)(skip +
                    ((size_t)b * T + t) * SKIPC + mt * 16 + q * 4);
            }
    }

    // ---- GEMM2: 1x1 ----
    float4v zacc[4][2];
#pragma unroll
    for (int mt = 0; mt < 4; mt++)
#pragma unroll
        for (int nt = 0; nt < 2; nt++) zacc[mt][nt] = (float4v)(0.f);

    half8 gb[2];
#pragma unroll
    for (int nt = 0; nt < 2; nt++)
        gb[nt] = *(const half8*)&Gs[wv][nt * 16 + lcol][q * 8];

#pragma unroll
    for (int mt = 0; mt < 4; mt++) {
        half8 af = *(const half8*)(w2l + ((size_t)(mt * 16 + lcol) * 32 + q * 8));
#pragma unroll
        for (int nt = 0; nt < 2; nt++)
            zacc[mt][nt] = __builtin_amdgcn_mfma_f32_16x16x32_f16(
                af, gb[nt], zacc[mt][nt], 0, 0, 0);
    }

    // ---- epilogue: float4 everywhere ----
#pragma unroll
    for (int mt = 0; mt < 2; mt++)
#pragma unroll
        for (int nt = 0; nt < 2; nt++) {
            int t = tcol + nt * 16 + lcol;
            size_t off = ((size_t)b * T + t) * RES + mt * 16 + q * 4;
            float4v hv = *(const float4v*)(h_in + off);
            *(float4v*)(h_out + off) = hv + zacc[mt][nt];
        }
#pragma unroll
    for (int mt = 0; mt < 2; mt++)
#pragma unroll
        for (int nt = 0; nt < 2; nt++) {
            int t = tcol + nt * 16 + lcol;
            size_t off = ((size_t)b * T + t) * SKIPC + mt * 16 + q * 4;
            float4v z = zacc[mt + 2][nt];
            if (FIRST) *(float4v*)(skip + off) = z;
            else       *(float4v*)(skip + off) = skv[mt][nt] + z;
        }
}

// ---------------- post2: tanh(skip[B][T][32]) -> conv 32->16 k3 -> tanh -----
// LDS-staged: block stages tanh(skip) rows [t0-2, t0+256) once with coalesced
// float4, conv reads LDS. out16 stays [B][16][T] for post3.
#define P2_TILE 256
__global__ __launch_bounds__(256) void post2_kernel(
        const float* __restrict__ skip,
        const float* __restrict__ w,    // [16][32][3]
        float* __restrict__ out16) {
    __shared__ float st[(P2_TILE + 2) * 33];   // rows t0-2..t0+255, stride 33

    const int tid = threadIdx.x;
    const int t0 = blockIdx.x * P2_TILE;
    const int b = blockIdx.y;

    const int total4 = ((P2_TILE + 2) * 32) / 4;   // 2064 float4 chunks
    for (int ci = tid; ci < total4; ci += 256) {
        int flat = ci * 4;
        int row = flat >> 5;
        int c = flat & 31;
        int ts = t0 - 2 + row;
        float4v v = (float4v)(0.f);
        if (ts >= 0)
            v = *(const float4v*)(skip + ((size_t)b * T + ts) * SKIPC + c);
        float* dst = &st[row * 33 + c];
        dst[0] = fast_tanh(v[0]);
        dst[1] = fast_tanh(v[1]);
        dst[2] = fast_tanh(v[2]);
        dst[3] = fast_tanh(v[3]);
    }
    __syncthreads();

    const int t = t0 + tid;
    float acc[16];
#pragma unroll
    for (int o = 0; o < 16; o++) acc[o] = 0.f;
#pragma unroll 4
    for (int c = 0; c < 32; c++) {
        float s0 = st[(tid + 0) * 33 + c];   // t-2
        float s1 = st[(tid + 1) * 33 + c];   // t-1
        float s2 = st[(tid + 2) * 33 + c];   // t
#pragma unroll
        for (int o = 0; o < 16; o++) {
            const float* wo = w + (o * 32 + c) * 3;
            acc[o] += wo[0] * s0 + wo[1] * s1 + wo[2] * s2;
        }
    }
#pragma unroll
    for (int o = 0; o < 16; o++)
        out16[((size_t)(b * 16 + o)) * T + t] = fast_tanh(acc[o]);
}

// ---------------- post3: conv 16->8 k3 -> tanh ----------------
__global__ void post3_kernel(const float* __restrict__ in16,
                             const float* __restrict__ w,    // [8][16][3]
                             float* __restrict__ out8) {
    int t = blockIdx.x * blockDim.x + threadIdx.x;
    int b = blockIdx.y;
    float acc[8];
#pragma unroll
    for (int o = 0; o < 8; o++) acc[o] = 0.f;
    for (int c = 0; c < 16; c++) {
        const float* sc = in16 + ((size_t)(b * 16 + c)) * T;
        float v2 = sc[t];
        float v1 = (t >= 1) ? sc[t - 1] : 0.f;
        float v0 = (t >= 2) ? sc[t - 2] : 0.f;
#pragma unroll
        for (int o = 0; o < 8; o++) {
            const float* wo = w + (o * 16 + c) * 3;
            acc[o] += wo[0] * v0 + wo[1] * v1 + wo[2] * v2;
        }
    }
#pragma unroll
    for (int o = 0; o < 8; o++)
        out8[((size_t)(b * 8 + o)) * T + t] = fast_tanh(acc[o]);
}

// ---------------- post4: conv 8->1 k3 -> tanh ----------------
__global__ void post4_kernel(const float* __restrict__ in8,
                             const float* __restrict__ w,    // [1][8][3]
                             float* __restrict__ out1) {
    int t = blockIdx.x * blockDim.x + threadIdx.x;
    int b = blockIdx.y;
    float acc = 0.f;
#pragma unroll
    for (int c = 0; c < 8; c++) {
        const float* sc = in8 + ((size_t)(b * 8 + c)) * T;
        float v2 = sc[t];
        float v1 = (t >= 1) ? sc[t - 1] : 0.f;
        float v0 = (t >= 2) ? sc[t - 2] : 0.f;
        const float* wo = w + c * 3;
        acc += wo[0] * v0 + wo[1] * v1 + wo[2] * v2;
    }
    out1[(size_t)b * T + t] = fast_tanh(acc);
}

// ---------------- vnn head: lin(k=16) + quadratic Volterra ----------------
__global__ void vnn_kernel(const float* __restrict__ in1,   // [B][T]
                           const float* __restrict__ w1,    // [1][1][16]
                           const float* __restrict__ w2,    // [6][1][16]
                           float* __restrict__ out) {       // [B][T]
    int t = blockIdx.x * blockDim.x + threadIdx.x;
    int b = blockIdx.y;
    const float* xb = in1 + (size_t)b * T;
    float tap[16];
#pragma unroll
    for (int k = 0; k < 16; k++) {
        int ti = t - 15 + k;
        tap[k] = (ti >= 0) ? xb[ti] : 0.f;
    }
    float lin = 0.f;
#pragma unroll
    for (int k = 0; k < 16; k++) lin += w1[k] * tap[k];
    float s[6];
#pragma unroll
    for (int q = 0; q < 6; q++) {
        float a = 0.f;
#pragma unroll
        for (int k = 0; k < 16; k++) a += w2[q * 16 + k] * tap[k];
        s[q] = a;
    }
    float quad = s[0] * s[3] + s[1] * s[4] + s[2] * s[5];
    out[(size_t)b * T + t] = lin + quad;
}

extern "C" void kernel_launch(void* const* d_in, const int* in_sizes, int n_in,
                              void* d_out, int out_size, void* d_ws, size_t ws_size,
                              hipStream_t stream) {
    const float* x       = (const float*)d_in[0];
    const float* conv1_w = (const float*)d_in[1];
    const float* res_w1  = (const float*)d_in[2];
    const float* res_w2  = (const float*)d_in[3];
    const float* post2_w = (const float*)d_in[4];
    const float* post3_w = (const float*)d_in[5];
    const float* post4_w = (const float*)d_in[6];
    const float* vnn1_w  = (const float*)d_in[7];
    const float* vnn2_w  = (const float*)d_in[8];
    float* out = (float*)d_out;

    char* ws = (char*)d_ws;
    const size_t SZ_H    = (size_t)B * RES * T * 4;
    const size_t SZ_O16  = (size_t)B * 16 * T * 4;
    const size_t SZ_O8   = (size_t)B * 8 * T * 4;
    const size_t SZ_O1   = (size_t)B * 1 * T * 4;
    float*     hA    = (float*)(ws);
    float*     hB    = (float*)(ws + SZ_H);
    float*     skip  = (float*)(ws + 2 * SZ_H);
    float*     out16 = (float*)(ws + 3 * SZ_H);
    float*     out8  = (float*)(ws + 3 * SZ_H + SZ_O16);
    float*     out1  = (float*)(ws + 3 * SZ_H + SZ_O16 + SZ_O8);
    _Float16*  w1f   = (_Float16*)(ws + 3 * SZ_H + SZ_O16 + SZ_O8 + SZ_O1);
    _Float16*  w2f   = (_Float16*)(ws + 3 * SZ_H + SZ_O16 + SZ_O8 + SZ_O1
                                      + (size_t)NDIL * 3 * 64 * 32 * 2);

    dim3 blk(256);
    dim3 grd(T / 256, B);     // conv1/post3/post4/vnn: 125 x 8
    dim3 grdR(T / 128, B);    // res layers: 250 x 8

    repack_weights_f16<<<dim3((NDIL * 3 * 64 * 32 + 255) / 256), blk, 0, stream>>>(
        res_w1, res_w2, w1f, w2f);

    conv1_kernel<<<grd, blk, 0, stream>>>(x, conv1_w, hA);

    const float* cur = hA;
    float* nxt = hB;
    for (int l = 0; l < NLAYERS; l++) {
        int i = l % NDIL;
        int d = 1 << i;
        const _Float16* w1l = w1f + (size_t)i * 3 * 64 * 32;
        const _Float16* w2l = w2f + (size_t)i * 64 * 32;
        if (l == 0)
            res_layer_mfma<true><<<grdR, blk, 0, stream>>>(cur, nxt, skip, w1l, w2l, d);
        else
            res_layer_mfma<false><<<grdR, blk, 0, stream>>>(cur, nxt, skip, w1l, w2l, d);
        const float* tmp = nxt;
        nxt = (float*)cur;
        cur = tmp;
    }

    post2_kernel<<<dim3(T / P2_TILE, B), blk, 0, stream>>>(skip, post2_w, out16);
    post3_kernel<<<grd, blk, 0, stream>>>(out16, post3_w, out8);
    post4_kernel<<<grd, blk, 0, stream>>>(out8, post4_w, out1);
    vnn_kernel<<<grd, blk, 0, stream>>>(out1, vnn1_w, vnn2_w, out);
}

// Round 13
// 610.440 us; speedup vs baseline: 5.5594x; 1.3667x over previous
//
#include <hip/hip_runtime.h>
#include <math.h>

#define T 32000
#define B 8
#define RES 32
#define SKIPC 32
#define NDIL 10
#define NLAYERS 20

typedef __attribute__((ext_vector_type(8))) _Float16 half8;
typedef __attribute__((ext_vector_type(4))) _Float16 half4;
typedef __attribute__((ext_vector_type(4))) float float4v;

// ---------------- fast transcendentals ----------------
__device__ __forceinline__ float fast_rcp(float x) { return __builtin_amdgcn_rcpf(x); }
__device__ __forceinline__ float fast_exp2(float x) { return __builtin_amdgcn_exp2f(x); }
__device__ __forceinline__ float fast_sigmoid(float x) {
    return fast_rcp(1.f + fast_exp2(-1.4426950408889634f * x));
}
__device__ __forceinline__ float fast_tanh(float x) {
    return 1.f - 2.f * fast_rcp(1.f + fast_exp2(2.8853900817779268f * x));
}

// ---------------- weight repack to fp16 ----------------
// res_w1: [10][64][32][3] -> w1f: [10][3][64][32] fp16  (tap-major, c contig)
// res_w2: [10][64][32]    -> w2f: [10][64][32] fp16
__global__ void repack_weights_f16(const float* __restrict__ w1,
                                   const float* __restrict__ w2,
                                   _Float16* __restrict__ w1f,
                                   _Float16* __restrict__ w2f) {
    int idx = blockIdx.x * blockDim.x + threadIdx.x;
    if (idx < NDIL * 3 * 64 * 32) {
        int i = idx;
        int c = i % 32; i /= 32;
        int o = i % 64; i /= 64;
        int kt = i % 3; i /= 3;
        int l = i;
        w1f[idx] = (_Float16)w1[((l * 64 + o) * 32 + c) * 3 + kt];
    }
    if (idx < NDIL * 64 * 32) {
        w2f[idx] = (_Float16)w2[idx];
    }
}

// ---------------- conv1: [B,1,T] -> h[B][T][RES] fp16 channel-contiguous ----
__global__ void conv1_kernel(const float* __restrict__ x,
                             const float* __restrict__ w,   // [32][1][3]
                             _Float16* __restrict__ h) {
    int t = blockIdx.x * blockDim.x + threadIdx.x;
    int b = blockIdx.y;
    if (t >= T) return;
    const float* xb = x + (size_t)b * T;
    float x2 = xb[t];
    float x1 = (t >= 1) ? xb[t - 1] : 0.f;
    float x0 = (t >= 2) ? xb[t - 2] : 0.f;
    _Float16* hr = h + ((size_t)b * T + t) * RES;
#pragma unroll
    for (int o = 0; o < RES; o += 8) {
        half8 v;
#pragma unroll
        for (int r = 0; r < 8; r++)
            v[r] = (_Float16)(w[(o + r) * 3 + 0] * x0 + w[(o + r) * 3 + 1] * x1
                            + w[(o + r) * 3 + 2] * x2);
        *(half8*)(hr + o) = v;
    }
}

// ---------------- residual layer via f16 MFMA, fp16 h, barrier-free ---------
// h stored fp16 [B][T][32]: the MFMA B-fragment (8 consecutive channels at
// one t) is ONE 16-byte half8 load — zero conversion instructions. skip stays
// fp32 (20-deep RMW chain). G exchange intra-wave via wave-private LDS slab
// + wave_barrier (compile-time ordering; HW DS ops in-order per wave).
template <bool FIRST>
__global__ __launch_bounds__(256) void res_layer_mfma(
        const _Float16* __restrict__ h_in, _Float16* __restrict__ h_out,
        float* __restrict__ skip,
        const _Float16* __restrict__ w1l,   // [3][64][32] this layer
        const _Float16* __restrict__ w2l,   // [64][32] this layer
        int d) {
    __shared__ _Float16 Gs[4][32][40];      // 10240 B, per-wave slabs

    const int tid = threadIdx.x;
    const int t0 = blockIdx.x * 128;
    const int b = blockIdx.y;
    const int lane = tid & 63;
    const int wv = tid >> 6;
    const int n0 = wv * 32;
    const int lcol = lane & 15;
    const int q = lane >> 4;
    const _Float16* hb = h_in + (size_t)b * T * RES;

    // ---- direct B-frag loads: 6 x one half8 ----
    half8 bf[2][3];
    const half8 zero8 = (half8)(_Float16)0.f;
    if (t0 >= 2 * d) {                      // interior block (uniform branch)
#pragma unroll
        for (int nt = 0; nt < 2; nt++)
#pragma unroll
            for (int kt = 0; kt < 3; kt++) {
                int tb = t0 + n0 + nt * 16 + lcol - (2 - kt) * d;
                bf[nt][kt] = *(const half8*)(hb + (size_t)tb * RES + q * 8);
            }
    } else {
#pragma unroll
        for (int nt = 0; nt < 2; nt++)
#pragma unroll
            for (int kt = 0; kt < 3; kt++) {
                int tb = t0 + n0 + nt * 16 + lcol - (2 - kt) * d;
                bool ok = tb >= 0;
                half8 p = *(const half8*)(hb + (size_t)(ok ? tb : 0) * RES + q * 8);
                bf[nt][kt] = ok ? p : zero8;
            }
    }

    // ---- GEMM1: conv ----
    float4v acc[4][2];
#pragma unroll
    for (int mt = 0; mt < 4; mt++)
#pragma unroll
        for (int nt = 0; nt < 2; nt++) acc[mt][nt] = (float4v)(0.f);

#pragma unroll
    for (int mt = 0; mt < 4; mt++) {
#pragma unroll
        for (int kt = 0; kt < 3; kt++) {
            half8 af = *(const half8*)(w1l +
                ((size_t)(kt * 64 + mt * 16 + lcol) * 32 + q * 8));
#pragma unroll
            for (int nt = 0; nt < 2; nt++)
                acc[mt][nt] = __builtin_amdgcn_mfma_f32_16x16x32_f16(
                    af, bf[nt][kt], acc[mt][nt], 0, 0, 0);
        }
    }

    // ---- gate (lane-local o <-> o+32 pairing), write to wave-private LDS ----
#pragma unroll
    for (int pp = 0; pp < 2; pp++)
#pragma unroll
        for (int nt = 0; nt < 2; nt++) {
            half4 gh;
#pragma unroll
            for (int r = 0; r < 4; r++) {
                float a0 = acc[pp][nt][r];
                float a1 = acc[pp + 2][nt][r];
                gh[r] = (_Float16)(fast_tanh(a0) * fast_sigmoid(a1));
            }
            *(half4*)&Gs[wv][nt * 16 + lcol][pp * 16 + q * 4] = gh;
        }
    // cross-lane within wave: pin compiler ordering (HW DS ops in-order/wave)
    __builtin_amdgcn_wave_barrier();

    // ---- skip prefetch (float4; latency hides under GEMM2) ----
    const int tcol = t0 + n0;
    float4v skv[2][2];
    if (!FIRST) {
#pragma unroll
        for (int mt = 0; mt < 2; mt++)
#pragma unroll
            for (int nt = 0; nt < 2; nt++) {
                int t = tcol + nt * 16 + lcol;
                skv[mt][nt] = *(const float4v*)(skip +
                    ((size_t)b * T + t) * SKIPC + mt * 16 + q * 4);
            }
    }

    // ---- GEMM2: 1x1 ----
    float4v zacc[4][2];
#pragma unroll
    for (int mt = 0; mt < 4; mt++)
#pragma unroll
        for (int nt = 0; nt < 2; nt++) zacc[mt][nt] = (float4v)(0.f);

    half8 gb[2];
#pragma unroll
    for (int nt = 0; nt < 2; nt++)
        gb[nt] = *(const half8*)&Gs[wv][nt * 16 + lcol][q * 8];

#pragma unroll
    for (int mt = 0; mt < 4; mt++) {
        half8 af = *(const half8*)(w2l + ((size_t)(mt * 16 + lcol) * 32 + q * 8));
#pragma unroll
        for (int nt = 0; nt < 2; nt++)
            zacc[mt][nt] = __builtin_amdgcn_mfma_f32_16x16x32_f16(
                af, gb[nt], zacc[mt][nt], 0, 0, 0);
    }

    // ---- epilogue ----
    // h: read half4 (L1-hot, same lines as kt=2 taps), add in fp32, store half4
#pragma unroll
    for (int mt = 0; mt < 2; mt++)
#pragma unroll
        for (int nt = 0; nt < 2; nt++) {
            int t = tcol + nt * 16 + lcol;
            size_t off = ((size_t)b * T + t) * RES + mt * 16 + q * 4;
            half4 hv = *(const half4*)(h_in + off);
            half4 hw;
#pragma unroll
            for (int r = 0; r < 4; r++)
                hw[r] = (_Float16)((float)hv[r] + zacc[mt][nt][r]);
            *(half4*)(h_out + off) = hw;
        }
    // skip: fp32 float4 RMW
#pragma unroll
    for (int mt = 0; mt < 2; mt++)
#pragma unroll
        for (int nt = 0; nt < 2; nt++) {
            int t = tcol + nt * 16 + lcol;
            size_t off = ((size_t)b * T + t) * SKIPC + mt * 16 + q * 4;
            float4v z = zacc[mt + 2][nt];
            if (FIRST) *(float4v*)(skip + off) = z;
            else       *(float4v*)(skip + off) = skv[mt][nt] + z;
        }
}

// ---------------- post2: tanh(skip[B][T][32]) -> conv 32->16 k3 -> tanh -----
// LDS-staged coalesced float4 staging; out16 stays [B][16][T] for post3.
#define P2_TILE 256
__global__ __launch_bounds__(256) void post2_kernel(
        const float* __restrict__ skip,
        const float* __restrict__ w,    // [16][32][3]
        float* __restrict__ out16) {
    __shared__ float st[(P2_TILE + 2) * 33];   // rows t0-2..t0+255, stride 33

    const int tid = threadIdx.x;
    const int t0 = blockIdx.x * P2_TILE;
    const int b = blockIdx.y;

    const int total4 = ((P2_TILE + 2) * 32) / 4;   // 2064 float4 chunks
    for (int ci = tid; ci < total4; ci += 256) {
        int flat = ci * 4;
        int row = flat >> 5;
        int c = flat & 31;
        int ts = t0 - 2 + row;
        float4v v = (float4v)(0.f);
        if (ts >= 0)
            v = *(const float4v*)(skip + ((size_t)b * T + ts) * SKIPC + c);
        float* dst = &st[row * 33 + c];
        dst[0] = fast_tanh(v[0]);
        dst[1] = fast_tanh(v[1]);
        dst[2] = fast_tanh(v[2]);
        dst[3] = fast_tanh(v[3]);
    }
    __syncthreads();

    const int t = t0 + tid;
    float acc[16];
#pragma unroll
    for (int o = 0; o < 16; o++) acc[o] = 0.f;
#pragma unroll 4
    for (int c = 0; c < 32; c++) {
        float s0 = st[(tid + 0) * 33 + c];   // t-2
        float s1 = st[(tid + 1) * 33 + c];   // t-1
        float s2 = st[(tid + 2) * 33 + c];   // t
#pragma unroll
        for (int o = 0; o < 16; o++) {
            const float* wo = w + (o * 32 + c) * 3;
            acc[o] += wo[0] * s0 + wo[1] * s1 + wo[2] * s2;
        }
    }
#pragma unroll
    for (int o = 0; o < 16; o++)
        out16[((size_t)(b * 16 + o)) * T + t] = fast_tanh(acc[o]);
}

// ---------------- post3: conv 16->8 k3 -> tanh ----------------
__global__ void post3_kernel(const float* __restrict__ in16,
                             const float* __restrict__ w,    // [8][16][3]
                             float* __restrict__ out8) {
    int t = blockIdx.x * blockDim.x + threadIdx.x;
    int b = blockIdx.y;
    float acc[8];
#pragma unroll
    for (int o = 0; o < 8; o++) acc[o] = 0.f;
    for (int c = 0; c < 16; c++) {
        const float* sc = in16 + ((size_t)(b * 16 + c)) * T;
        float v2 = sc[t];
        float v1 = (t >= 1) ? sc[t - 1] : 0.f;
        float v0 = (t >= 2) ? sc[t - 2] : 0.f;
#pragma unroll
        for (int o = 0; o < 8; o++) {
            const float* wo = w + (o * 16 + c) * 3;
            acc[o] += wo[0] * v0 + wo[1] * v1 + wo[2] * v2;
        }
    }
#pragma unroll
    for (int o = 0; o < 8; o++)
        out8[((size_t)(b * 8 + o)) * T + t] = fast_tanh(acc[o]);
}

// ---------------- post4: conv 8->1 k3 -> tanh ----------------
__global__ void post4_kernel(const float* __restrict__ in8,
                             const float* __restrict__ w,    // [1][8][3]
                             float* __restrict__ out1) {
    int t = blockIdx.x * blockDim.x + threadIdx.x;
    int b = blockIdx.y;
    float acc = 0.f;
#pragma unroll
    for (int c = 0; c < 8; c++) {
        const float* sc = in8 + ((size_t)(b * 8 + c)) * T;
        float v2 = sc[t];
        float v1 = (t >= 1) ? sc[t - 1] : 0.f;
        float v0 = (t >= 2) ? sc[t - 2] : 0.f;
        const float* wo = w + c * 3;
        acc += wo[0] * v0 + wo[1] * v1 + wo[2] * v2;
    }
    out1[(size_t)b * T + t] = fast_tanh(acc);
}

// ---------------- vnn head: lin(k=16) + quadratic Volterra ----------------
__global__ void vnn_kernel(const float* __restrict__ in1,   // [B][T]
                           const float* __restrict__ w1,    // [1][1][16]
                           const float* __restrict__ w2,    // [6][1][16]
                           float* __restrict__ out) {       // [B][T]
    int t = blockIdx.x * blockDim.x + threadIdx.x;
    int b = blockIdx.y;
    const float* xb = in1 + (size_t)b * T;
    float tap[16];
#pragma unroll
    for (int k = 0; k < 16; k++) {
        int ti = t - 15 + k;
        tap[k] = (ti >= 0) ? xb[ti] : 0.f;
    }
    float lin = 0.f;
#pragma unroll
    for (int k = 0; k < 16; k++) lin += w1[k] * tap[k];
    float s[6];
#pragma unroll
    for (int q = 0; q < 6; q++) {
        float a = 0.f;
#pragma unroll
        for (int k = 0; k < 16; k++) a += w2[q * 16 + k] * tap[k];
        s[q] = a;
    }
    float quad = s[0] * s[3] + s[1] * s[4] + s[2] * s[5];
    out[(size_t)b * T + t] = lin + quad;
}

extern "C" void kernel_launch(void* const* d_in, const int* in_sizes, int n_in,
                              void* d_out, int out_size, void* d_ws, size_t ws_size,
                              hipStream_t stream) {
    const float* x       = (const float*)d_in[0];
    const float* conv1_w = (const float*)d_in[1];
    const float* res_w1  = (const float*)d_in[2];
    const float* res_w2  = (const float*)d_in[3];
    const float* post2_w = (const float*)d_in[4];
    const float* post3_w = (const float*)d_in[5];
    const float* post4_w = (const float*)d_in[6];
    const float* vnn1_w  = (const float*)d_in[7];
    const float* vnn2_w  = (const float*)d_in[8];
    float* out = (float*)d_out;

    char* ws = (char*)d_ws;
    const size_t SZ_HF   = (size_t)B * RES * T * 2;     // fp16 h buffers
    const size_t SZ_SKIP = (size_t)B * SKIPC * T * 4;   // fp32 skip
    const size_t SZ_O16  = (size_t)B * 16 * T * 4;
    const size_t SZ_O8   = (size_t)B * 8 * T * 4;
    const size_t SZ_O1   = (size_t)B * 1 * T * 4;
    _Float16*  hA    = (_Float16*)(ws);
    _Float16*  hB    = (_Float16*)(ws + SZ_HF);
    float*     skip  = (float*)(ws + 2 * SZ_HF);
    float*     out16 = (float*)(ws + 2 * SZ_HF + SZ_SKIP);
    float*     out8  = (float*)(ws + 2 * SZ_HF + SZ_SKIP + SZ_O16);
    float*     out1  = (float*)(ws + 2 * SZ_HF + SZ_SKIP + SZ_O16 + SZ_O8);
    _Float16*  w1f   = (_Float16*)(ws + 2 * SZ_HF + SZ_SKIP + SZ_O16 + SZ_O8 + SZ_O1);
    _Float16*  w2f   = (_Float16*)(ws + 2 * SZ_HF + SZ_SKIP + SZ_O16 + SZ_O8 + SZ_O1
                                      + (size_t)NDIL * 3 * 64 * 32 * 2);

    dim3 blk(256);
    dim3 grd(T / 256, B);     // conv1/post3/post4/vnn: 125 x 8
    dim3 grdR(T / 128, B);    // res layers: 250 x 8

    repack_weights_f16<<<dim3((NDIL * 3 * 64 * 32 + 255) / 256), blk, 0, stream>>>(
        res_w1, res_w2, w1f, w2f);

    conv1_kernel<<<grd, blk, 0, stream>>>(x, conv1_w, hA);

    const _Float16* cur = hA;
    _Float16* nxt = hB;
    for (int l = 0; l < NLAYERS; l++) {
        int i = l % NDIL;
        int d = 1 << i;
        const _Float16* w1l = w1f + (size_t)i * 3 * 64 * 32;
        const _Float16* w2l = w2f + (size_t)i * 64 * 32;
        if (l == 0)
            res_layer_mfma<true><<<grdR, blk, 0, stream>>>(cur, nxt, skip, w1l, w2l, d);
        else
            res_layer_mfma<false><<<grdR, blk, 0, stream>>>(cur, nxt, skip, w1l, w2l, d);
        const _Float16* tmp = nxt;
        nxt = (_Float16*)cur;
        cur = tmp;
    }

    post2_kernel<<<dim3(T / P2_TILE, B), blk, 0, stream>>>(skip, post2_w, out16);
    post3_kernel<<<grd, blk, 0, stream>>>(out16, post3_w, out8);
    post4_kernel<<<grd, blk, 0, stream>>>(out8, post4_w, out1);
    vnn_kernel<<<grd, blk, 0, stream>>>(out1, vnn1_w, vnn2_w, out);
}

// Round 14
// 532.242 us; speedup vs baseline: 6.3762x; 1.1469x over previous
//
#include <hip/hip_runtime.h>
#include <math.h>

#define T 32000
#define B 8
#define RES 32
#define SKIPC 32
#define NDIL 10
#define NLAYERS 20

typedef __attribute__((ext_vector_type(8))) _Float16 half8;
typedef __attribute__((ext_vector_type(4))) _Float16 half4;
typedef __attribute__((ext_vector_type(4))) float float4v;

// ---------------- fast transcendentals ----------------
__device__ __forceinline__ float fast_rcp(float x) { return __builtin_amdgcn_rcpf(x); }
__device__ __forceinline__ float fast_exp2(float x) { return __builtin_amdgcn_exp2f(x); }
__device__ __forceinline__ float fast_sigmoid(float x) {
    return fast_rcp(1.f + fast_exp2(-1.4426950408889634f * x));
}
__device__ __forceinline__ float fast_tanh(float x) {
    return 1.f - 2.f * fast_rcp(1.f + fast_exp2(2.8853900817779268f * x));
}

// ---------------- weight repack to fp16 ----------------
// res_w1: [10][64][32][3] -> w1f: [10][3][64][32] fp16  (tap-major, c contig)
// res_w2: [10][64][32]    -> w2f: [10][64][32] fp16
__global__ void repack_weights_f16(const float* __restrict__ w1,
                                   const float* __restrict__ w2,
                                   _Float16* __restrict__ w1f,
                                   _Float16* __restrict__ w2f) {
    int idx = blockIdx.x * blockDim.x + threadIdx.x;
    if (idx < NDIL * 3 * 64 * 32) {
        int i = idx;
        int c = i % 32; i /= 32;
        int o = i % 64; i /= 64;
        int kt = i % 3; i /= 3;
        int l = i;
        w1f[idx] = (_Float16)w1[((l * 64 + o) * 32 + c) * 3 + kt];
    }
    if (idx < NDIL * 64 * 32) {
        w2f[idx] = (_Float16)w2[idx];
    }
}

// ---------------- conv1: [B,1,T] -> h[B][T][RES] fp16 channel-contiguous ----
__global__ void conv1_kernel(const float* __restrict__ x,
                             const float* __restrict__ w,   // [32][1][3]
                             _Float16* __restrict__ h) {
    int t = blockIdx.x * blockDim.x + threadIdx.x;
    int b = blockIdx.y;
    if (t >= T) return;
    const float* xb = x + (size_t)b * T;
    float x2 = xb[t];
    float x1 = (t >= 1) ? xb[t - 1] : 0.f;
    float x0 = (t >= 2) ? xb[t - 2] : 0.f;
    _Float16* hr = h + ((size_t)b * T + t) * RES;
#pragma unroll
    for (int o = 0; o < RES; o += 8) {
        half8 v;
#pragma unroll
        for (int r = 0; r < 8; r++)
            v[r] = (_Float16)(w[(o + r) * 3 + 0] * x0 + w[(o + r) * 3 + 1] * x1
                            + w[(o + r) * 3 + 2] * x2);
        *(half8*)(hr + o) = v;
    }
}

// ---------------- residual layer via f16 MFMA, fp16 h + fp16 skip -----------
// h fp16 [B][T][32]: B-fragment = ONE 16-byte half8 load. skip fp16 [B][T][32]
// (R14): RMW traffic halves — add done in fp32, stored fp16; random-walk error
// over 19 RMWs is damped ~0.008x by the post chain (tripwire: absmax).
// G exchange intra-wave via wave-private LDS slab + wave_barrier.
template <bool FIRST>
__global__ __launch_bounds__(256) void res_layer_mfma(
        const _Float16* __restrict__ h_in, _Float16* __restrict__ h_out,
        _Float16* __restrict__ skip,
        const _Float16* __restrict__ w1l,   // [3][64][32] this layer
        const _Float16* __restrict__ w2l,   // [64][32] this layer
        int d) {
    __shared__ _Float16 Gs[4][32][40];      // 10240 B, per-wave slabs

    const int tid = threadIdx.x;
    const int t0 = blockIdx.x * 128;
    const int b = blockIdx.y;
    const int lane = tid & 63;
    const int wv = tid >> 6;
    const int n0 = wv * 32;
    const int lcol = lane & 15;
    const int q = lane >> 4;
    const _Float16* hb = h_in + (size_t)b * T * RES;

    // ---- direct B-frag loads: 6 x one half8 ----
    half8 bf[2][3];
    const half8 zero8 = (half8)(_Float16)0.f;
    if (t0 >= 2 * d) {                      // interior block (uniform branch)
#pragma unroll
        for (int nt = 0; nt < 2; nt++)
#pragma unroll
            for (int kt = 0; kt < 3; kt++) {
                int tb = t0 + n0 + nt * 16 + lcol - (2 - kt) * d;
                bf[nt][kt] = *(const half8*)(hb + (size_t)tb * RES + q * 8);
            }
    } else {
#pragma unroll
        for (int nt = 0; nt < 2; nt++)
#pragma unroll
            for (int kt = 0; kt < 3; kt++) {
                int tb = t0 + n0 + nt * 16 + lcol - (2 - kt) * d;
                bool ok = tb >= 0;
                half8 p = *(const half8*)(hb + (size_t)(ok ? tb : 0) * RES + q * 8);
                bf[nt][kt] = ok ? p : zero8;
            }
    }

    // ---- GEMM1: conv ----
    float4v acc[4][2];
#pragma unroll
    for (int mt = 0; mt < 4; mt++)
#pragma unroll
        for (int nt = 0; nt < 2; nt++) acc[mt][nt] = (float4v)(0.f);

#pragma unroll
    for (int mt = 0; mt < 4; mt++) {
#pragma unroll
        for (int kt = 0; kt < 3; kt++) {
            half8 af = *(const half8*)(w1l +
                ((size_t)(kt * 64 + mt * 16 + lcol) * 32 + q * 8));
#pragma unroll
            for (int nt = 0; nt < 2; nt++)
                acc[mt][nt] = __builtin_amdgcn_mfma_f32_16x16x32_f16(
                    af, bf[nt][kt], acc[mt][nt], 0, 0, 0);
        }
    }

    // ---- gate (lane-local o <-> o+32 pairing), write to wave-private LDS ----
#pragma unroll
    for (int pp = 0; pp < 2; pp++)
#pragma unroll
        for (int nt = 0; nt < 2; nt++) {
            half4 gh;
#pragma unroll
            for (int r = 0; r < 4; r++) {
                float a0 = acc[pp][nt][r];
                float a1 = acc[pp + 2][nt][r];
                gh[r] = (_Float16)(fast_tanh(a0) * fast_sigmoid(a1));
            }
            *(half4*)&Gs[wv][nt * 16 + lcol][pp * 16 + q * 4] = gh;
        }
    // cross-lane within wave: pin compiler ordering (HW DS ops in-order/wave)
    __builtin_amdgcn_wave_barrier();

    // ---- skip prefetch (half4; latency hides under GEMM2) ----
    const int tcol = t0 + n0;
    half4 skv[2][2];
    if (!FIRST) {
#pragma unroll
        for (int mt = 0; mt < 2; mt++)
#pragma unroll
            for (int nt = 0; nt < 2; nt++) {
                int t = tcol + nt * 16 + lcol;
                skv[mt][nt] = *(const half4*)(skip +
                    ((size_t)b * T + t) * SKIPC + mt * 16 + q * 4);
            }
    }

    // ---- GEMM2: 1x1 ----
    float4v zacc[4][2];
#pragma unroll
    for (int mt = 0; mt < 4; mt++)
#pragma unroll
        for (int nt = 0; nt < 2; nt++) zacc[mt][nt] = (float4v)(0.f);

    half8 gb[2];
#pragma unroll
    for (int nt = 0; nt < 2; nt++)
        gb[nt] = *(const half8*)&Gs[wv][nt * 16 + lcol][q * 8];

#pragma unroll
    for (int mt = 0; mt < 4; mt++) {
        half8 af = *(const half8*)(w2l + ((size_t)(mt * 16 + lcol) * 32 + q * 8));
#pragma unroll
        for (int nt = 0; nt < 2; nt++)
            zacc[mt][nt] = __builtin_amdgcn_mfma_f32_16x16x32_f16(
                af, gb[nt], zacc[mt][nt], 0, 0, 0);
    }

    // ---- epilogue ----
    // h: read half4 (L1-hot, same lines as kt=2 taps), add in fp32, store half4
#pragma unroll
    for (int mt = 0; mt < 2; mt++)
#pragma unroll
        for (int nt = 0; nt < 2; nt++) {
            int t = tcol + nt * 16 + lcol;
            size_t off = ((size_t)b * T + t) * RES + mt * 16 + q * 4;
            half4 hv = *(const half4*)(h_in + off);
            half4 hw;
#pragma unroll
            for (int r = 0; r < 4; r++)
                hw[r] = (_Float16)((float)hv[r] + zacc[mt][nt][r]);
            *(half4*)(h_out + off) = hw;
        }
    // skip: fp16 RMW (fp32 add, fp16 store)
#pragma unroll
    for (int mt = 0; mt < 2; mt++)
#pragma unroll
        for (int nt = 0; nt < 2; nt++) {
            int t = tcol + nt * 16 + lcol;
            size_t off = ((size_t)b * T + t) * SKIPC + mt * 16 + q * 4;
            half4 sw;
#pragma unroll
            for (int r = 0; r < 4; r++) {
                float z = zacc[mt + 2][nt][r];
                sw[r] = (_Float16)(FIRST ? z : (float)skv[mt][nt][r] + z);
            }
            *(half4*)(skip + off) = sw;
        }
}

// ---------------- post2: tanh(skip fp16 [B][T][32]) -> conv 32->16 k3 -> tanh
// LDS-staged coalesced half8 staging; out16 stays [B][16][T] for post3.
#define P2_TILE 256
__global__ __launch_bounds__(256) void post2_kernel(
        const _Float16* __restrict__ skip,
        const float* __restrict__ w,    // [16][32][3]
        float* __restrict__ out16) {
    __shared__ float st[(P2_TILE + 2) * 33];   // rows t0-2..t0+255, stride 33

    const int tid = threadIdx.x;
    const int t0 = blockIdx.x * P2_TILE;
    const int b = blockIdx.y;

    const int total8 = ((P2_TILE + 2) * 32) / 8;   // 1032 half8 chunks
    for (int ci = tid; ci < total8; ci += 256) {
        int flat = ci * 8;
        int row = flat >> 5;
        int c = flat & 31;
        int ts = t0 - 2 + row;
        half8 v = (half8)(_Float16)0.f;
        if (ts >= 0)
            v = *(const half8*)(skip + ((size_t)b * T + ts) * SKIPC + c);
        float* dst = &st[row * 33 + c];
#pragma unroll
        for (int r = 0; r < 8; r++)
            dst[r] = fast_tanh((float)v[r]);
    }
    __syncthreads();

    const int t = t0 + tid;
    float acc[16];
#pragma unroll
    for (int o = 0; o < 16; o++) acc[o] = 0.f;
#pragma unroll 4
    for (int c = 0; c < 32; c++) {
        float s0 = st[(tid + 0) * 33 + c];   // t-2
        float s1 = st[(tid + 1) * 33 + c];   // t-1
        float s2 = st[(tid + 2) * 33 + c];   // t
#pragma unroll
        for (int o = 0; o < 16; o++) {
            const float* wo = w + (o * 32 + c) * 3;
            acc[o] += wo[0] * s0 + wo[1] * s1 + wo[2] * s2;
        }
    }
#pragma unroll
    for (int o = 0; o < 16; o++)
        out16[((size_t)(b * 16 + o)) * T + t] = fast_tanh(acc[o]);
}

// ---------------- post3: conv 16->8 k3 -> tanh ----------------
__global__ void post3_kernel(const float* __restrict__ in16,
                             const float* __restrict__ w,    // [8][16][3]
                             float* __restrict__ out8) {
    int t = blockIdx.x * blockDim.x + threadIdx.x;
    int b = blockIdx.y;
    float acc[8];
#pragma unroll
    for (int o = 0; o < 8; o++) acc[o] = 0.f;
    for (int c = 0; c < 16; c++) {
        const float* sc = in16 + ((size_t)(b * 16 + c)) * T;
        float v2 = sc[t];
        float v1 = (t >= 1) ? sc[t - 1] : 0.f;
        float v0 = (t >= 2) ? sc[t - 2] : 0.f;
#pragma unroll
        for (int o = 0; o < 8; o++) {
            const float* wo = w + (o * 16 + c) * 3;
            acc[o] += wo[0] * v0 + wo[1] * v1 + wo[2] * v2;
        }
    }
#pragma unroll
    for (int o = 0; o < 8; o++)
        out8[((size_t)(b * 8 + o)) * T + t] = fast_tanh(acc[o]);
}

// ---------------- post4: conv 8->1 k3 -> tanh ----------------
__global__ void post4_kernel(const float* __restrict__ in8,
                             const float* __restrict__ w,    // [1][8][3]
                             float* __restrict__ out1) {
    int t = blockIdx.x * blockDim.x + threadIdx.x;
    int b = blockIdx.y;
    float acc = 0.f;
#pragma unroll
    for (int c = 0; c < 8; c++) {
        const float* sc = in8 + ((size_t)(b * 8 + c)) * T;
        float v2 = sc[t];
        float v1 = (t >= 1) ? sc[t - 1] : 0.f;
        float v0 = (t >= 2) ? sc[t - 2] : 0.f;
        const float* wo = w + c * 3;
        acc += wo[0] * v0 + wo[1] * v1 + wo[2] * v2;
    }
    out1[(size_t)b * T + t] = fast_tanh(acc);
}

// ---------------- vnn head: lin(k=16) + quadratic Volterra ----------------
__global__ void vnn_kernel(const float* __restrict__ in1,   // [B][T]
                           const float* __restrict__ w1,    // [1][1][16]
                           const float* __restrict__ w2,    // [6][1][16]
                           float* __restrict__ out) {       // [B][T]
    int t = blockIdx.x * blockDim.x + threadIdx.x;
    int b = blockIdx.y;
    const float* xb = in1 + (size_t)b * T;
    float tap[16];
#pragma unroll
    for (int k = 0; k < 16; k++) {
        int ti = t - 15 + k;
        tap[k] = (ti >= 0) ? xb[ti] : 0.f;
    }
    float lin = 0.f;
#pragma unroll
    for (int k = 0; k < 16; k++) lin += w1[k] * tap[k];
    float s[6];
#pragma unroll
    for (int q = 0; q < 6; q++) {
        float a = 0.f;
#pragma unroll
        for (int k = 0; k < 16; k++) a += w2[q * 16 + k] * tap[k];
        s[q] = a;
    }
    float quad = s[0] * s[3] + s[1] * s[4] + s[2] * s[5];
    out[(size_t)b * T + t] = lin + quad;
}

extern "C" void kernel_launch(void* const* d_in, const int* in_sizes, int n_in,
                              void* d_out, int out_size, void* d_ws, size_t ws_size,
                              hipStream_t stream) {
    const float* x       = (const float*)d_in[0];
    const float* conv1_w = (const float*)d_in[1];
    const float* res_w1  = (const float*)d_in[2];
    const float* res_w2  = (const float*)d_in[3];
    const float* post2_w = (const float*)d_in[4];
    const float* post3_w = (const float*)d_in[5];
    const float* post4_w = (const float*)d_in[6];
    const float* vnn1_w  = (const float*)d_in[7];
    const float* vnn2_w  = (const float*)d_in[8];
    float* out = (float*)d_out;

    char* ws = (char*)d_ws;
    const size_t SZ_HF   = (size_t)B * RES * T * 2;     // fp16 h buffers
    const size_t SZ_SKIP = (size_t)B * SKIPC * T * 2;   // fp16 skip
    const size_t SZ_O16  = (size_t)B * 16 * T * 4;
    const size_t SZ_O8   = (size_t)B * 8 * T * 4;
    const size_t SZ_O1   = (size_t)B * 1 * T * 4;
    _Float16*  hA    = (_Float16*)(ws);
    _Float16*  hB    = (_Float16*)(ws + SZ_HF);
    _Float16*  skip  = (_Float16*)(ws + 2 * SZ_HF);
    float*     out16 = (float*)(ws + 2 * SZ_HF + SZ_SKIP);
    float*     out8  = (float*)(ws + 2 * SZ_HF + SZ_SKIP + SZ_O16);
    float*     out1  = (float*)(ws + 2 * SZ_HF + SZ_SKIP + SZ_O16 + SZ_O8);
    _Float16*  w1f   = (_Float16*)(ws + 2 * SZ_HF + SZ_SKIP + SZ_O16 + SZ_O8 + SZ_O1);
    _Float16*  w2f   = (_Float16*)(ws + 2 * SZ_HF + SZ_SKIP + SZ_O16 + SZ_O8 + SZ_O1
                                      + (size_t)NDIL * 3 * 64 * 32 * 2);

    dim3 blk(256);
    dim3 grd(T / 256, B);     // conv1/post3/post4/vnn: 125 x 8
    dim3 grdR(T / 128, B);    // res layers: 250 x 8

    repack_weights_f16<<<dim3((NDIL * 3 * 64 * 32 + 255) / 256), blk, 0, stream>>>(
        res_w1, res_w2, w1f, w2f);

    conv1_kernel<<<grd, blk, 0, stream>>>(x, conv1_w, hA);

    const _Float16* cur = hA;
    _Float16* nxt = hB;
    for (int l = 0; l < NLAYERS; l++) {
        int i = l % NDIL;
        int d = 1 << i;
        const _Float16* w1l = w1f + (size_t)i * 3 * 64 * 32;
        const _Float16* w2l = w2f + (size_t)i * 64 * 32;
        if (l == 0)
            res_layer_mfma<true><<<grdR, blk, 0, stream>>>(cur, nxt, skip, w1l, w2l, d);
        else
            res_layer_mfma<false><<<grdR, blk, 0, stream>>>(cur, nxt, skip, w1l, w2l, d);
        const _Float16* tmp = nxt;
        nxt = (_Float16*)cur;
        cur = tmp;
    }

    post2_kernel<<<dim3(T / P2_TILE, B), blk, 0, stream>>>(skip, post2_w, out16);
    post3_kernel<<<grd, blk, 0, stream>>>(out16, post3_w, out8);
    post4_kernel<<<grd, blk, 0, stream>>>(out8, post4_w, out1);
    vnn_kernel<<<grd, blk, 0, stream>>>(out1, vnn1_w, vnn2_w, out);
}